// Round 3
// baseline (92.979 us; speedup 1.0000x reference)
//
#include <hip/hip_runtime.h>

#define NB_IMG   2048
#define GSQ      169                  // 13*13
#define NCELLS   (NB_IMG * GSQ)       // 346112
#define NCH      125
#define NANCH    5
#define BATCH_FLOATS (NCH * GSQ)      // 21125
#define XBLOCKS  (NCELLS / 256)       // 1352 (exact)
#define NBLK     (XBLOCKS * NANCH)    // 6760
#define PART_BYTES ((size_t)NBLK * 8 * sizeof(double))   // 432,640 B

// Per-block partial slots: [0..3] coord sq, [4] conf sq obj, [5] conf sq noobj,
// [6] class sq (this anchor), [7] obj count (this anchor)
// Atomic-path acc layout (16 doubles): [0..5] as above, [6..10] per-anchor class,
// [11..15] per-anchor count.

template<bool ATOMIC>
__global__ __launch_bounds__(256) void detloss_main(
    const float* __restrict__ det,
    const float* __restrict__ gt,
    const float* __restrict__ aw,
    const float* __restrict__ ah,
    double* __restrict__ ws)
{
    const int k   = blockIdx.y;                    // anchor, uniform per block
    const int cid = blockIdx.x * 256 + threadIdx.x;
    const int b    = cid / GSQ;
    const int cell = cid - b * GSQ;

    const float* dbase = det + (size_t)b * BATCH_FLOATS + cell;  // anchor-0 ch c at [c*GSQ]
    const float* gbase = gt  + (size_t)b * BATCH_FLOATS + cell;
    const float* dk = dbase + k * 25 * GSQ;
    const float* gk = gbase + k * 25 * GSQ;

    // anchor-0 box (drives IoU for every anchor)
    const float px = dbase[0 * GSQ];
    const float py = dbase[1 * GSQ];
    const float dw = dbase[2 * GSQ];
    const float dh = dbase[3 * GSQ];
    const float gx = gbase[0 * GSQ];
    const float gy = gbase[1 * GSQ];
    const float gw = gbase[2 * GSQ];
    const float gh = gbase[3 * GSQ];
    const float a2 = (gw - gx + 1.0f) * (gh - gy + 1.0f);

    const float pw = dw * aw[k];                  // aw[k]: scalar (block-uniform) load
    const float ph = dh * ah[k];
    const float x1 = fmaxf(px, gx);
    const float y1 = fmaxf(py, gy);
    const float x2 = fminf(pw, gw);
    const float y2 = fminf(ph, gh);
    const float inter = (x2 - x1 + 1.0f) * (y2 - y1 + 1.0f);
    const float a1    = (pw - px + 1.0f) * (ph - py + 1.0f);
    const float iou   = inter / (a1 + a2 - inter);

    const float g4v  = gk[4 * GSQ];
    const float conf = dk[4 * GSQ] * (iou >= 0.0f ? iou : 0.0f);  // NaN -> 0 like jnp.where
    const float d4   = conf - g4v;
    const float d4sq = d4 * d4;
    const bool  obj  = (g4v == 1.0f);
    const float m    = obj ? 1.0f : 0.0f;

    float S0, S1, S2, S3, S4, S5, Scls, Ccnt;
    float dd;
    dd = dk[0 * GSQ] - gk[0 * GSQ]; S0 = m * dd * dd;
    dd = dk[1 * GSQ] - gk[1 * GSQ]; S1 = m * dd * dd;
    dd = dk[2 * GSQ] - gk[2 * GSQ]; S2 = m * dd * dd;
    dd = dk[3 * GSQ] - gk[3 * GSQ]; S3 = m * dd * dd;

    S4 = obj ? d4sq : 0.0f;     // selects, not mask-mul: avoid inf*0 -> NaN
    S5 = obj ? 0.0f : d4sq;

    float sc = 0.0f;
    #pragma unroll
    for (int j = 0; j < 20; ++j) {
        dd = dk[(5 + j) * GSQ] - gk[(5 + j) * GSQ];
        sc += dd * dd;
    }
    Scls = m * sc;
    Ccnt = m;

    // ---- block reduction of 8 partials ----
    float vals[8] = {S0, S1, S2, S3, S4, S5, Scls, Ccnt};
    #pragma unroll
    for (int i = 0; i < 8; ++i) {
        #pragma unroll
        for (int off = 32; off > 0; off >>= 1)
            vals[i] += __shfl_down(vals[i], off, 64);
    }

    __shared__ float part[4][8];
    const int wave = threadIdx.x >> 6;
    const int lane = threadIdx.x & 63;
    if (lane == 0) {
        #pragma unroll
        for (int i = 0; i < 8; ++i) part[wave][i] = vals[i];
    }
    __syncthreads();

    if (threadIdx.x < 8) {
        const double s = (double)part[0][threadIdx.x] + (double)part[1][threadIdx.x] +
                         (double)part[2][threadIdx.x] + (double)part[3][threadIdx.x];
        if (ATOMIC) {
            const int i = threadIdx.x;
            const int slot = (i < 6) ? i : (i == 6 ? 6 + k : 11 + k);
            atomicAdd(&ws[slot], s);
        } else {
            ws[((size_t)k * XBLOCKS + blockIdx.x) * 8 + threadIdx.x] = s;
        }
    }
}

__device__ __forceinline__ void write_outputs(const double* a, float* out)
{
    const double cnt = a[11] + a[12] + a[13] + a[14] + a[15];
    const double coord = (cnt > 0.0) ? (a[0] + a[1] + a[2] + a[3]) / cnt : 0.0;
    const double s4    = (cnt > 0.0) ? a[4] / cnt : 0.0;
    const double obj_loss = 5.0 * coord + s4;

    const double cntno  = (double)NCELLS * (double)NANCH - cnt;
    const double no_obj = (cntno > 0.0) ? 0.5 * a[5] / cntno : 0.0;

    double confsum = 0.0;
    for (int k = 0; k < NANCH; ++k) {
        const double ck = a[11 + k];
        if (ck > 0.0) confsum += a[6 + k] / ck;
    }
    const double loss = obj_loss + no_obj + confsum;
    out[0] = (float)loss;
    out[1] = (float)obj_loss;
    out[2] = (float)no_obj;
    out[3] = (float)confsum;
}

// partials-path reduce: sum 6760 records of 8 doubles -> 16 slots -> outputs
__global__ __launch_bounds__(256) void detloss_reduce(
    const double* __restrict__ ws, float* __restrict__ out)
{
    double loc[16];
    #pragma unroll
    for (int i = 0; i < 16; ++i) loc[i] = 0.0;

    for (int rec = threadIdx.x; rec < NBLK; rec += 256) {
        const int k = rec / XBLOCKS;
        const double* p = ws + (size_t)rec * 8;
        loc[0] += p[0]; loc[1] += p[1]; loc[2] += p[2]; loc[3] += p[3];
        loc[4] += p[4]; loc[5] += p[5];
        loc[6 + k]  += p[6];
        loc[11 + k] += p[7];
    }

    #pragma unroll
    for (int i = 0; i < 16; ++i) {
        #pragma unroll
        for (int off = 32; off > 0; off >>= 1)
            loc[i] += __shfl_down(loc[i], off, 64);
    }

    __shared__ double red[4][16];
    const int wave = threadIdx.x >> 6;
    const int lane = threadIdx.x & 63;
    if (lane == 0) {
        #pragma unroll
        for (int i = 0; i < 16; ++i) red[wave][i] = loc[i];
    }
    __syncthreads();

    if (threadIdx.x == 0) {
        double a[16];
        #pragma unroll
        for (int i = 0; i < 16; ++i)
            a[i] = red[0][i] + red[1][i] + red[2][i] + red[3][i];
        write_outputs(a, out);
    }
}

// atomic-path finalize
__global__ void detloss_final(const double* __restrict__ acc, float* __restrict__ out)
{
    if (threadIdx.x == 0 && blockIdx.x == 0) {
        double a[16];
        for (int i = 0; i < 16; ++i) a[i] = acc[i];
        write_outputs(a, out);
    }
}

extern "C" void kernel_launch(void* const* d_in, const int* in_sizes, int n_in,
                              void* d_out, int out_size, void* d_ws, size_t ws_size,
                              hipStream_t stream)
{
    const float* det = (const float*)d_in[0];
    const float* gt  = (const float*)d_in[1];
    const float* aw  = (const float*)d_in[2];
    const float* ah  = (const float*)d_in[3];
    double* ws  = (double*)d_ws;
    float*  out = (float*)d_out;

    if (ws_size >= PART_BYTES) {
        detloss_main<false><<<dim3(XBLOCKS, NANCH), 256, 0, stream>>>(det, gt, aw, ah, ws);
        detloss_reduce<<<1, 256, 0, stream>>>(ws, out);
    } else {
        hipMemsetAsync(ws, 0, 16 * sizeof(double), stream);
        detloss_main<true><<<dim3(XBLOCKS, NANCH), 256, 0, stream>>>(det, gt, aw, ah, ws);
        detloss_final<<<1, 64, 0, stream>>>(ws, out);
    }
}

// Round 4
// 76.172 us; speedup vs baseline: 1.2206x; 1.2206x over previous
//
#include <hip/hip_runtime.h>

#define NB_IMG   2048
#define GSQ      169                  // 13*13
#define NCELLS   (NB_IMG * GSQ)       // 346112
#define NANCH    5
#define ANCH_FLOATS  (25 * GSQ)       // 4225
#define BATCH_FLOATS (125 * GSQ)      // 21125
#define CLS_FLOATS   (20 * GSQ)       // 3380 class floats per (b,anchor)
#define REC_SLOTS 16
#define PART_BYTES ((size_t)NB_IMG * REC_SLOTS * sizeof(double))  // 262144

// Record slots: [0] coord sq (all 4 ch, all anchors)  [1] conf sq obj
// [2] conf sq noobj  [3..7] per-anchor class sq  [8..12] per-anchor obj count

template<bool ATOMIC>
__global__ __launch_bounds__(256) void detloss_main(
    const float* __restrict__ det,
    const float* __restrict__ gt,
    const float* __restrict__ aw,
    const float* __restrict__ ah,
    double* __restrict__ ws)
{
    __shared__ float mask_lds[NANCH][GSQ];
    __shared__ float red[4][13];

    const int b   = blockIdx.x;
    const int tid = threadIdx.x;
    const size_t bbase = (size_t)b * BATCH_FLOATS;

    float Scoord = 0.f, S4 = 0.f, S5 = 0.f;
    float Scls[NANCH] = {0.f, 0.f, 0.f, 0.f, 0.f};
    float Ccnt[NANCH] = {0.f, 0.f, 0.f, 0.f, 0.f};

    // ---------- Phase A: box/conf channels (scalar, 20% of bytes) ----------
    if (tid < GSQ) {
        const int cell = tid;
        const float* dbase = det + bbase + cell;
        const float* gbase = gt  + bbase + cell;

        // anchor-0 box drives IoU for all anchors
        const float px = dbase[0 * GSQ];
        const float py = dbase[1 * GSQ];
        const float dw = dbase[2 * GSQ];
        const float dh = dbase[3 * GSQ];
        const float gx = gbase[0 * GSQ];
        const float gy = gbase[1 * GSQ];
        const float gw = gbase[2 * GSQ];
        const float gh = gbase[3 * GSQ];
        const float a2 = (gw - gx + 1.0f) * (gh - gy + 1.0f);

        #pragma unroll
        for (int k = 0; k < NANCH; ++k) {
            const float* dk = dbase + k * ANCH_FLOATS;
            const float* gk = gbase + k * ANCH_FLOATS;

            const float pw = dw * aw[k];
            const float ph = dh * ah[k];
            const float x1 = fmaxf(px, gx);
            const float y1 = fmaxf(py, gy);
            const float x2 = fminf(pw, gw);
            const float y2 = fminf(ph, gh);
            const float inter = (x2 - x1 + 1.0f) * (y2 - y1 + 1.0f);
            const float a1    = (pw - px + 1.0f) * (ph - py + 1.0f);
            const float iou   = inter / (a1 + a2 - inter);

            const float g4v  = gk[4 * GSQ];
            const float conf = dk[4 * GSQ] * (iou >= 0.0f ? iou : 0.0f); // NaN -> 0
            const float d4   = conf - g4v;
            const float d4sq = d4 * d4;
            const bool  obj  = (g4v == 1.0f);
            const float m    = obj ? 1.0f : 0.0f;

            float dd;
            dd = dk[0 * GSQ] - gk[0 * GSQ]; Scoord += m * dd * dd;
            dd = dk[1 * GSQ] - gk[1 * GSQ]; Scoord += m * dd * dd;
            dd = dk[2 * GSQ] - gk[2 * GSQ]; Scoord += m * dd * dd;
            dd = dk[3 * GSQ] - gk[3 * GSQ]; Scoord += m * dd * dd;

            S4 += obj ? d4sq : 0.0f;   // selects: avoid inf*0 -> NaN
            S5 += obj ? 0.0f : d4sq;

            Ccnt[k] = m;
            mask_lds[k][cell] = m;
        }
    }
    __syncthreads();   // masks visible to all threads

    // ---------- Phase B: class channels (float4 stream, 80% of bytes) ----------
    #pragma unroll
    for (int a = 0; a < NANCH; ++a) {
        const size_t s   = bbase + (size_t)a * ANCH_FLOATS + 5 * GSQ; // first class float
        const int    off = (int)(s & 3);
        const size_t A   = s - off;                                   // 16B-aligned
        const float4* d4p = (const float4*)det + (A >> 2);
        const float4* g4p = (const float4*)gt  + (A >> 2);
        const int n4 = 845 + (off ? 1 : 0);

        float accl = 0.f;
        for (int i = tid; i < n4; i += 256) {
            const float4 dv = d4p[i];
            const float4 gv = g4p[i];
            const int rel0 = 4 * i - off;
            const float de[4] = {dv.x, dv.y, dv.z, dv.w};
            const float ge[4] = {gv.x, gv.y, gv.z, gv.w};
            #pragma unroll
            for (int e = 0; e < 4; ++e) {
                const int r = rel0 + e;
                if ((unsigned)r < (unsigned)CLS_FLOATS) {
                    const int cell = (int)((unsigned)r % (unsigned)GSQ);
                    const float m  = mask_lds[a][cell];
                    const float dd = de[e] - ge[e];
                    accl += m * dd * dd;
                }
            }
        }
        Scls[a] = accl;
    }

    // ---------- block reduction of 13 partials ----------
    float vals[13] = {Scoord, S4, S5,
                      Scls[0], Scls[1], Scls[2], Scls[3], Scls[4],
                      Ccnt[0], Ccnt[1], Ccnt[2], Ccnt[3], Ccnt[4]};
    #pragma unroll
    for (int i = 0; i < 13; ++i) {
        #pragma unroll
        for (int off2 = 32; off2 > 0; off2 >>= 1)
            vals[i] += __shfl_down(vals[i], off2, 64);
    }

    const int wave = tid >> 6;
    const int lane = tid & 63;
    if (lane == 0) {
        #pragma unroll
        for (int i = 0; i < 13; ++i) red[wave][i] = vals[i];
    }
    __syncthreads();

    if (tid < 13) {
        const double s = (double)red[0][tid] + (double)red[1][tid] +
                         (double)red[2][tid] + (double)red[3][tid];
        if (ATOMIC) atomicAdd(&ws[tid], s);
        else        ws[(size_t)b * REC_SLOTS + tid] = s;
    }
}

__device__ __forceinline__ void write_outputs(const double* a, float* out)
{
    const double cnt = a[8] + a[9] + a[10] + a[11] + a[12];
    const double coord = (cnt > 0.0) ? a[0] / cnt : 0.0;
    const double s4    = (cnt > 0.0) ? a[1] / cnt : 0.0;
    const double obj_loss = 5.0 * coord + s4;

    const double cntno  = (double)NCELLS * (double)NANCH - cnt;
    const double no_obj = (cntno > 0.0) ? 0.5 * a[2] / cntno : 0.0;

    double confsum = 0.0;
    for (int k = 0; k < NANCH; ++k) {
        const double ck = a[8 + k];
        if (ck > 0.0) confsum += a[3 + k] / ck;
    }
    const double loss = obj_loss + no_obj + confsum;
    out[0] = (float)loss;
    out[1] = (float)obj_loss;
    out[2] = (float)no_obj;
    out[3] = (float)confsum;
}

__global__ __launch_bounds__(256) void detloss_reduce(
    const double* __restrict__ ws, float* __restrict__ out)
{
    double loc[13];
    #pragma unroll
    for (int i = 0; i < 13; ++i) loc[i] = 0.0;

    for (int rec = threadIdx.x; rec < NB_IMG; rec += 256) {
        const double* p = ws + (size_t)rec * REC_SLOTS;
        #pragma unroll
        for (int i = 0; i < 13; ++i) loc[i] += p[i];
    }

    #pragma unroll
    for (int i = 0; i < 13; ++i) {
        #pragma unroll
        for (int off = 32; off > 0; off >>= 1)
            loc[i] += __shfl_down(loc[i], off, 64);
    }

    __shared__ double red[4][13];
    const int wave = threadIdx.x >> 6;
    const int lane = threadIdx.x & 63;
    if (lane == 0) {
        #pragma unroll
        for (int i = 0; i < 13; ++i) red[wave][i] = loc[i];
    }
    __syncthreads();

    if (threadIdx.x == 0) {
        double a[13];
        #pragma unroll
        for (int i = 0; i < 13; ++i)
            a[i] = red[0][i] + red[1][i] + red[2][i] + red[3][i];
        write_outputs(a, out);
    }
}

__global__ void detloss_final(const double* __restrict__ acc, float* __restrict__ out)
{
    if (threadIdx.x == 0 && blockIdx.x == 0) {
        double a[13];
        for (int i = 0; i < 13; ++i) a[i] = acc[i];
        write_outputs(a, out);
    }
}

extern "C" void kernel_launch(void* const* d_in, const int* in_sizes, int n_in,
                              void* d_out, int out_size, void* d_ws, size_t ws_size,
                              hipStream_t stream)
{
    const float* det = (const float*)d_in[0];
    const float* gt  = (const float*)d_in[1];
    const float* aw  = (const float*)d_in[2];
    const float* ah  = (const float*)d_in[3];
    double* ws  = (double*)d_ws;
    float*  out = (float*)d_out;

    if (ws_size >= PART_BYTES) {
        detloss_main<false><<<NB_IMG, 256, 0, stream>>>(det, gt, aw, ah, ws);
        detloss_reduce<<<1, 256, 0, stream>>>(ws, out);
    } else {
        hipMemsetAsync(ws, 0, 13 * sizeof(double), stream);
        detloss_main<true><<<NB_IMG, 256, 0, stream>>>(det, gt, aw, ah, ws);
        detloss_final<<<1, 64, 0, stream>>>(ws, out);
    }
}

// Round 5
// 61.838 us; speedup vs baseline: 1.5036x; 1.2318x over previous
//
#include <hip/hip_runtime.h>

#define NB_IMG   2048
#define GSQ      169                  // 13*13
#define NCELLS   (NB_IMG * GSQ)       // 346112
#define NANCH    5
#define ANCH_FLOATS  (25 * GSQ)       // 4225
#define BATCH_FLOATS (125 * GSQ)      // 21125
#define CLS_FLOATS   (20 * GSQ)       // 3380 class floats per (b,anchor)
#define REC_SLOTS 16
#define PART_BYTES ((size_t)NB_IMG * REC_SLOTS * sizeof(double))  // 262144

// Record slots: [0] coord sq (all 4 ch, all anchors)  [1] conf sq obj
// [2] conf sq noobj  [3..7] per-anchor class sq  [8..12] per-anchor obj count

template<bool ATOMIC>
__global__ __launch_bounds__(256) void detloss_main(
    const float* __restrict__ det,
    const float* __restrict__ gt,
    const float* __restrict__ aw,
    const float* __restrict__ ah,
    double* __restrict__ ws)
{
    __shared__ unsigned long long mbits[NANCH][3];  // obj bitmask per anchor, cells 0..168
    __shared__ float red[4][13];

    const int b    = blockIdx.x;
    const int tid  = threadIdx.x;
    const int wave = tid >> 6;
    const int lane = tid & 63;
    const size_t bbase = (size_t)b * BATCH_FLOATS;

    float Scoord = 0.f, S4 = 0.f, S5 = 0.f;
    float Scls[NANCH] = {0.f, 0.f, 0.f, 0.f, 0.f};
    float Ccnt[NANCH] = {0.f, 0.f, 0.f, 0.f, 0.f};

    // ---------- Phase A: box/conf channels (scalar, 20% of bytes) ----------
    if (tid < GSQ) {
        const int cell = tid;
        const float* dbase = det + bbase + cell;
        const float* gbase = gt  + bbase + cell;

        // anchor-0 box drives IoU for all anchors
        const float px = dbase[0 * GSQ];
        const float py = dbase[1 * GSQ];
        const float dw = dbase[2 * GSQ];
        const float dh = dbase[3 * GSQ];
        const float gx = gbase[0 * GSQ];
        const float gy = gbase[1 * GSQ];
        const float gw = gbase[2 * GSQ];
        const float gh = gbase[3 * GSQ];
        const float a2 = (gw - gx + 1.0f) * (gh - gy + 1.0f);

        #pragma unroll
        for (int k = 0; k < NANCH; ++k) {
            const float* dk = dbase + k * ANCH_FLOATS;
            const float* gk = gbase + k * ANCH_FLOATS;

            const float pw = dw * aw[k];
            const float ph = dh * ah[k];
            const float x1 = fmaxf(px, gx);
            const float y1 = fmaxf(py, gy);
            const float x2 = fminf(pw, gw);
            const float y2 = fminf(ph, gh);
            const float inter = (x2 - x1 + 1.0f) * (y2 - y1 + 1.0f);
            const float a1    = (pw - px + 1.0f) * (ph - py + 1.0f);
            const float iou   = inter / (a1 + a2 - inter);

            const float g4v  = gk[4 * GSQ];
            const float conf = dk[4 * GSQ] * (iou >= 0.0f ? iou : 0.0f); // NaN -> 0
            const float d4   = conf - g4v;
            const float d4sq = d4 * d4;
            const bool  obj  = (g4v == 1.0f);
            const float m    = obj ? 1.0f : 0.0f;

            float dd;
            dd = dk[0 * GSQ] - gk[0 * GSQ]; Scoord += m * dd * dd;
            dd = dk[1 * GSQ] - gk[1 * GSQ]; Scoord += m * dd * dd;
            dd = dk[2 * GSQ] - gk[2 * GSQ]; Scoord += m * dd * dd;
            dd = dk[3 * GSQ] - gk[3 * GSQ]; Scoord += m * dd * dd;

            S4 += obj ? d4sq : 0.0f;   // selects: avoid inf*0 -> NaN
            S5 += obj ? 0.0f : d4sq;

            Ccnt[k] = m;

            // publish obj mask as ballot bits: cell = wave*64 + lane
            const unsigned long long bb = __ballot(obj);
            if (lane == 0) mbits[k][wave] = bb;   // wave in {0,1,2} here
        }
    }
    __syncthreads();   // masks visible to all threads

    // ---------- Phase B: class channels, load-gated on obj bits ----------
    const float4* dt4 = (const float4*)det;
    const float4* gt4 = (const float4*)gt;

    #pragma unroll 1
    for (int a = 0; a < NANCH; ++a) {
        const unsigned long long mb0 = mbits[a][0];
        const unsigned long long mb1 = mbits[a][1];
        const unsigned long long mb2 = mbits[a][2];
        if ((mb0 | mb1 | mb2) == 0ull) continue;   // whole slab empty (rare)

        const size_t s    = bbase + (size_t)a * ANCH_FLOATS + 5 * GSQ; // first class float
        const int    off  = (int)(s & 3);
        const size_t base4 = s >> 2;               // aligned-down float4 index
        const int    n4   = off ? 846 : 845;

        int r0    = 4 * tid - off;                 // rel offset of element 0 of my group
        int cell0 = r0 % GSQ; if (cell0 < 0) cell0 += GSQ;
        float accl = 0.f;

        for (int i = tid; i < n4; i += 256, r0 += 1024) {
            // gather 4 obj bits (register shifts on broadcast u64s; no LDS traffic)
            unsigned mask4 = 0;
            #pragma unroll
            for (int e = 0; e < 4; ++e) {
                int c = cell0 + e; c -= (c >= GSQ) ? GSQ : 0;
                const unsigned long long w = (c < 64) ? mb0 : ((c < 128) ? mb1 : mb2);
                unsigned bit = (unsigned)(w >> (c & 63)) & 1u;
                const int r = r0 + e;
                bit &= ((unsigned)r < (unsigned)CLS_FLOATS) ? 1u : 0u;
                mask4 |= bit << e;
            }
            if (mask4) {                            // skip loads when no obj cell
                const float4 dv = dt4[base4 + i];
                const float4 gv = gt4[base4 + i];
                const float de[4] = {dv.x, dv.y, dv.z, dv.w};
                const float ge[4] = {gv.x, gv.y, gv.z, gv.w};
                #pragma unroll
                for (int e = 0; e < 4; ++e) {
                    if (mask4 & (1u << e)) {        // m == 1 exactly
                        const float dd = de[e] - ge[e];
                        accl += dd * dd;
                    }
                }
            }
            cell0 += 10;                            // 1024 mod 169 == 10
            if (cell0 >= GSQ) cell0 -= GSQ;
        }
        Scls[a] = accl;
    }

    // ---------- block reduction of 13 partials ----------
    float vals[13] = {Scoord, S4, S5,
                      Scls[0], Scls[1], Scls[2], Scls[3], Scls[4],
                      Ccnt[0], Ccnt[1], Ccnt[2], Ccnt[3], Ccnt[4]};
    #pragma unroll
    for (int i = 0; i < 13; ++i) {
        #pragma unroll
        for (int off2 = 32; off2 > 0; off2 >>= 1)
            vals[i] += __shfl_down(vals[i], off2, 64);
    }

    if (lane == 0) {
        #pragma unroll
        for (int i = 0; i < 13; ++i) red[wave][i] = vals[i];
    }
    __syncthreads();

    if (tid < 13) {
        const double s = (double)red[0][tid] + (double)red[1][tid] +
                         (double)red[2][tid] + (double)red[3][tid];
        if (ATOMIC) atomicAdd(&ws[tid], s);
        else        ws[(size_t)b * REC_SLOTS + tid] = s;
    }
}

__device__ __forceinline__ void write_outputs(const double* a, float* out)
{
    const double cnt = a[8] + a[9] + a[10] + a[11] + a[12];
    const double coord = (cnt > 0.0) ? a[0] / cnt : 0.0;
    const double s4    = (cnt > 0.0) ? a[1] / cnt : 0.0;
    const double obj_loss = 5.0 * coord + s4;

    const double cntno  = (double)NCELLS * (double)NANCH - cnt;
    const double no_obj = (cntno > 0.0) ? 0.5 * a[2] / cntno : 0.0;

    double confsum = 0.0;
    for (int k = 0; k < NANCH; ++k) {
        const double ck = a[8 + k];
        if (ck > 0.0) confsum += a[3 + k] / ck;
    }
    const double loss = obj_loss + no_obj + confsum;
    out[0] = (float)loss;
    out[1] = (float)obj_loss;
    out[2] = (float)no_obj;
    out[3] = (float)confsum;
}

__global__ __launch_bounds__(256) void detloss_reduce(
    const double* __restrict__ ws, float* __restrict__ out)
{
    double loc[13];
    #pragma unroll
    for (int i = 0; i < 13; ++i) loc[i] = 0.0;

    for (int rec = threadIdx.x; rec < NB_IMG; rec += 256) {
        const double* p = ws + (size_t)rec * REC_SLOTS;
        #pragma unroll
        for (int i = 0; i < 13; ++i) loc[i] += p[i];
    }

    #pragma unroll
    for (int i = 0; i < 13; ++i) {
        #pragma unroll
        for (int off = 32; off > 0; off >>= 1)
            loc[i] += __shfl_down(loc[i], off, 64);
    }

    __shared__ double red[4][13];
    const int wave = threadIdx.x >> 6;
    const int lane = threadIdx.x & 63;
    if (lane == 0) {
        #pragma unroll
        for (int i = 0; i < 13; ++i) red[wave][i] = loc[i];
    }
    __syncthreads();

    if (threadIdx.x == 0) {
        double a[13];
        #pragma unroll
        for (int i = 0; i < 13; ++i)
            a[i] = red[0][i] + red[1][i] + red[2][i] + red[3][i];
        write_outputs(a, out);
    }
}

__global__ void detloss_final(const double* __restrict__ acc, float* __restrict__ out)
{
    if (threadIdx.x == 0 && blockIdx.x == 0) {
        double a[13];
        for (int i = 0; i < 13; ++i) a[i] = acc[i];
        write_outputs(a, out);
    }
}

extern "C" void kernel_launch(void* const* d_in, const int* in_sizes, int n_in,
                              void* d_out, int out_size, void* d_ws, size_t ws_size,
                              hipStream_t stream)
{
    const float* det = (const float*)d_in[0];
    const float* gt  = (const float*)d_in[1];
    const float* aw  = (const float*)d_in[2];
    const float* ah  = (const float*)d_in[3];
    double* ws  = (double*)d_ws;
    float*  out = (float*)d_out;

    if (ws_size >= PART_BYTES) {
        detloss_main<false><<<NB_IMG, 256, 0, stream>>>(det, gt, aw, ah, ws);
        detloss_reduce<<<1, 256, 0, stream>>>(ws, out);
    } else {
        hipMemsetAsync(ws, 0, 13 * sizeof(double), stream);
        detloss_main<true><<<NB_IMG, 256, 0, stream>>>(det, gt, aw, ah, ws);
        detloss_final<<<1, 64, 0, stream>>>(ws, out);
    }
}